// Round 12
// baseline (541.962 us; speedup 1.0000x reference)
//
#include <hip/hip_runtime.h>
#include <cstdint>
#include <cstddef>

typedef unsigned long long u64;

#define CIN   512
#define H     38
#define W     50
#define HW    1900
#define PH    40
#define PW    52
#define NA    17100
#define NSORT 32768
#define PRE   6000
#define POST  300
#define NW    94        // ceil(6000/64)
#define MTS   6016      // MT row stride (padded)
#define TOPN  6016      // padded top-k (>= PRE)
#define PB    8         // p-chunk for relu_heads (238 blocks ~ 1/CU)

// ANCHOR_BASE, fp32-exact decimal literals
__constant__ float c_AB[36] = {
  -37.254833f,  -82.50967f,   53.254833f,  98.50967f,
  -82.50967f,  -173.01933f,   98.50967f,  189.01933f,
 -173.01933f,  -354.03867f,  189.01933f,  370.03867f,
  -56.f, -56.f, 72.f, 72.f,
 -120.f,-120.f,136.f,136.f,
 -248.f,-248.f,264.f,264.f,
  -82.50967f,  -37.254833f,   98.50967f,  53.254833f,
 -173.01933f,  -82.50967f,   189.01933f,  98.50967f,
 -354.03867f, -173.01933f,   370.03867f, 189.01933f
};

// ----------------- fused prep: pad (4160 blks) + wtrans (1024 blks) ------------
__global__ __launch_bounds__(256) void prep_kernel(const float* __restrict__ x, float* __restrict__ xp,
                                                   const float* __restrict__ w1, float* __restrict__ wt) {
  __shared__ float tile[9][16][17];
  int b = blockIdx.x;
  if (b < 4160) {                                    // ---- pad ----
    int idx = b * 256 + threadIdx.x;                 // exactly 512*40*52
    int c   = idx / (PH * PW);
    int rem = idx - c * (PH * PW);
    int yy  = rem / PW;
    int xx  = rem - yy * PW;
    float v = 0.f;
    if (yy >= 1 && yy <= H && xx >= 1 && xx <= W)
      v = x[(size_t)c * HW + (yy - 1) * W + (xx - 1)];
    xp[idx] = v;
  } else {                                           // ---- wtrans ----
    int t2 = b - 4160;
    int o0 = (t2 & 31) * 16, i0 = (t2 >> 5) * 16;
    int tx = threadIdx.x & 15, ty = threadIdx.x >> 4;
    #pragma unroll
    for (int r = 0; r < 9; ++r)
      tile[r][tx][ty] = w1[((size_t)(o0 + ty) * CIN + (i0 + tx)) * 9 + r];
    __syncthreads();
    #pragma unroll
    for (int r = 0; r < 9; ++r)
      wt[((size_t)r * CIN + i0 + ty) * CIN + o0 + tx] = tile[r][ty][tx];
  }
}

// --------- conv1: A LDS-staged (r0-proven), B from global registers ------------
// r11 post-mortem: the 172us wall = 2 ds_read_b128/kk/wave (24 LDS-cyc vs 32
// FMA-cyc; 11.2 waves/CU -> 269 LDS cyc/CU-kk). B never needed LDS: per thread
// its 4 p-offsets are K-invariant and the channel walk is +PH*PW per kk ->
// uniform-base global_load (saddr+voffset) + 4x v_add_u32. A keeps the proven
// vector-LDS path (NOT r3's scalar drain; NOT r2's 64-bit addr mults).
// New budget/CU-kk: LDS 134 cyc (A only) ~ VALU 134 cyc -> ~2x FMA floor.
// Bit-exact: same B values (p>=HW threads load clamped in-bounds garbage but
// HW%4==0 -> no partial quads -> garbage never stored), same ii->jj fma order,
// same ascending-k sequence per output.
__global__ __launch_bounds__(256) void conv_gemm_kernel(const float* __restrict__ wt, const float* __restrict__ xp,
                                                        float* __restrict__ part) {
  __shared__ __align__(16) float As[16][64];
  const int tid   = threadIdx.x;
  const int obase = blockIdx.x * 64;
  const int pbase = blockIdx.y * 64;
  const int split = blockIdx.z;
  const int krow = tid >> 4;          // staging row 0..15
  const int c4   = (tid & 15) * 4;    // staging col
  const int to   = (tid & 15) * 4;    // output o quad
  const int tp   = (tid >> 4) * 4;    // output p quad

  // K-invariant per-thread B offsets (clamped; invalid p never stored)
  int boff[4];
  {
    int p0 = pbase + tp;
    #pragma unroll
    for (int j = 0; j < 4; ++j) {
      int p = p0 + j; if (p >= HW) p = HW - 1;
      int y = p / 50, xx = p - y * 50;
      boff[j] = y * PW + xx;
    }
  }

  float acc[4][4] = {};
  float av[4];

  #pragma unroll 1
  for (int kx = 0; kx < 3; ++kx) {
    const int kchunk = split * 1536 + kx * 512;      // ky = split, kx filter = kx
    const float* __restrict__ xpc = xp + split * PW + kx;   // wave-uniform base
    int i0 = boff[0], i1 = boff[1], i2 = boff[2], i3 = boff[3];  // 32-bit voffsets

    {  // A prefetch for first staging block of this chunk
      int k = kchunk + krow;
      const float* ap = &wt[(size_t)k * CIN + obase + c4];
      av[0] = ap[0]; av[1] = ap[1]; av[2] = ap[2]; av[3] = ap[3];
    }
    #pragma unroll 1
    for (int k0 = kchunk; k0 < kchunk + 512; k0 += 16) {
      __syncthreads();
      *(float4*)&As[krow][c4] = make_float4(av[0], av[1], av[2], av[3]);
      __syncthreads();
      if (k0 + 16 < kchunk + 512) {
        int k = k0 + 16 + krow;
        const float* ap = &wt[(size_t)k * CIN + obase + c4];
        av[0] = ap[0]; av[1] = ap[1]; av[2] = ap[2]; av[3] = ap[3];
      }
      #pragma unroll
      for (int kk = 0; kk < 16; ++kk) {
        float4 a4 = *(const float4*)&As[kk][to];
        float br[4];
        br[0] = xpc[i0]; br[1] = xpc[i1]; br[2] = xpc[i2]; br[3] = xpc[i3];
        float ar[4] = {a4.x, a4.y, a4.z, a4.w};
        #pragma unroll
        for (int ii = 0; ii < 4; ++ii)
          #pragma unroll
          for (int jj = 0; jj < 4; ++jj)
            acc[ii][jj] += ar[ii] * br[jj];
        i0 += PH * PW; i1 += PH * PW; i2 += PH * PW; i3 += PH * PW;
      }
    }
  }

  float* dst = part + (size_t)split * CIN * HW;
  #pragma unroll
  for (int ii = 0; ii < 4; ++ii) {
    int o = obase + to + ii;
    int p = pbase + tp;
    float* rowp = dst + (size_t)o * HW;
    if (p + 3 < HW) {
      *(float4*)&rowp[p] = make_float4(acc[ii][0], acc[ii][1], acc[ii][2], acc[ii][3]);
    } else {
      #pragma unroll
      for (int jj = 0; jj < 4; ++jj) if (p + jj < HW) rowp[p + jj] = acc[ii][jj];
    }
  }
}

// ---- fused relu+heads: h1 column slab in LDS, c2 out; h1 never materialized ---
__global__ __launch_bounds__(256) void relu_heads_kernel(const float* __restrict__ part, const float* __restrict__ b1,
                                                         const float* __restrict__ lw, const float* __restrict__ sw,
                                                         const float* __restrict__ lb, const float* __restrict__ sb,
                                                         float* __restrict__ c2) {
  __shared__ float h1c[CIN][PB];                     // 16KB
  const int tid = threadIdx.x;
  const int p0  = blockIdx.x * PB;
  // phase 1: relu slab
  for (int e = tid; e < CIN * PB; e += 256) {
    int o  = e >> 3;
    int pp = e & (PB - 1);
    int p  = p0 + pp;
    float v = 0.f;
    if (p < HW) {
      size_t idx = (size_t)o * HW + p;
      v = part[idx] + part[(size_t)CIN * HW + idx] + part[(size_t)2 * CIN * HW + idx] + b1[o];
      v = v > 0.f ? v : 0.f;
    }
    h1c[o][pp] = v;
  }
  __syncthreads();
  // phase 2: heads dots from LDS
  for (int u = tid; u < 54 * PB; u += 256) {
    int o  = u >> 3;
    int pp = u & (PB - 1);
    int p  = p0 + pp;
    const float* __restrict__ ap = (o < 36) ? (lw + (size_t)o * CIN) : (sw + (size_t)(o - 36) * CIN);
    float acc = 0.f;
    #pragma unroll 1
    for (int g = 0; g < CIN; g += 16) {
      float4 a0 = *(const float4*)(ap + g);
      float4 a1 = *(const float4*)(ap + g + 4);
      float4 a2 = *(const float4*)(ap + g + 8);
      float4 a3 = *(const float4*)(ap + g + 12);
      acc += a0.x * h1c[g +  0][pp];  acc += a0.y * h1c[g +  1][pp];
      acc += a0.z * h1c[g +  2][pp];  acc += a0.w * h1c[g +  3][pp];
      acc += a1.x * h1c[g +  4][pp];  acc += a1.y * h1c[g +  5][pp];
      acc += a1.z * h1c[g +  6][pp];  acc += a1.w * h1c[g +  7][pp];
      acc += a2.x * h1c[g +  8][pp];  acc += a2.y * h1c[g +  9][pp];
      acc += a2.z * h1c[g + 10][pp];  acc += a2.w * h1c[g + 11][pp];
      acc += a3.x * h1c[g + 12][pp];  acc += a3.y * h1c[g + 13][pp];
      acc += a3.z * h1c[g + 14][pp];  acc += a3.w * h1c[g + 15][pp];
    }
    if (p < HW) {
      float bias = (o < 36) ? lb[o] : sb[o - 36];
      c2[(size_t)o * HW + p] = acc + bias;
    }
  }
}

// ------- fused decode + LDS bitonic sort: 16 blocks, 2048 keys each ------------
__global__ __launch_bounds__(256) void decode_sort_kernel(const float* __restrict__ c2, float* __restrict__ roi,
                                                          u64* __restrict__ keys) {
  __shared__ u64 s[2048];
  const int tid = threadIdx.x;
  const int nbase = blockIdx.x * 2048;
  for (int i = tid; i < 2048; i += 256) {
    int n = nbase + i;
    u64 key;
    if (n >= NA) {
      key = ~0ull;
    } else {
      unsigned p = (unsigned)n / 9u;
      unsigned a = (unsigned)n - p * 9u;
      unsigned y = p / 50u;
      unsigned xu = p - y * 50u;
      float dy = c2[(a * 4 + 0) * HW + p];
      float dx = c2[(a * 4 + 1) * HW + p];
      float dh = c2[(a * 4 + 2) * HW + p];
      float dw = c2[(a * 4 + 3) * HW + p];
      float fg = c2[(37 + a * 2) * HW + p];         // score channel a*2+1, rows offset 36
      float sy = (float)(y * 16u), sx = (float)(xu * 16u);
      float ay1 = sy + c_AB[a * 4 + 0], ax1 = sx + c_AB[a * 4 + 1];
      float ay2 = sy + c_AB[a * 4 + 2], ax2 = sx + c_AB[a * 4 + 3];
      float ahh = ay2 - ay1, aww = ax2 - ax1;
      float acy = ay1 + 0.5f * ahh, acx = ax1 + 0.5f * aww;
      float cy = dy * ahh + acy, cx = dx * aww + acx;
      float hh = expf(dh) * ahh, ww = expf(dw) * aww;
      float y1 = cy - 0.5f * hh, x1 = cx - 0.5f * ww;
      float y2 = cy + 0.5f * hh, x2 = cx + 0.5f * ww;
      y1 = fminf(fmaxf(y1, 0.f), 608.f); x1 = fminf(fmaxf(x1, 0.f), 800.f);
      y2 = fminf(fmaxf(y2, 0.f), 608.f); x2 = fminf(fmaxf(x2, 0.f), 800.f);
      *(float4*)&roi[(size_t)n * 4] = make_float4(y1, x1, y2, x2);
      bool valid = ((y2 - y1) >= 16.f) && ((x2 - x1) >= 16.f);
      float sc = valid ? fg : -__builtin_huge_valf();
      unsigned m = __float_as_uint(sc);
      m = (m & 0x80000000u) ? ~m : (m | 0x80000000u);  // monotone map
      unsigned km = ~m;                                 // ascending = descending score
      key = ((u64)km << 32) | (unsigned)n;
    }
    s[i] = key;
  }
  __syncthreads();
  for (int k = 2; k <= 2048; k <<= 1) {
    for (int j = k >> 1; j > 0; j >>= 1) {
      for (int i = tid; i < 2048; i += 256) {
        int l = i ^ j;
        if (l > i) {
          u64 xa = s[i], xb = s[l];
          bool up = ((i & k) == 0);
          if ((xa > xb) == up) { s[i] = xb; s[l] = xa; }
        }
      }
      __syncthreads();
    }
  }
  for (int i = tid; i < 2048; i += 256) keys[nbase + i] = s[i];
}

// ------------------------------ merge-path helper ------------------------------
__device__ inline void merge_path(const u64* __restrict__ A, int nA, const u64* __restrict__ B, int nB,
                                  u64* __restrict__ dst, int d0, int cnt, int outLimit) {
  if (d0 >= outLimit || d0 >= nA + nB) return;
  int lo = d0 > nB ? d0 - nB : 0;
  int hi = d0 < nA ? d0 : nA;
  while (lo < hi) {
    int mid = (lo + hi) >> 1;
    if (A[mid] <= B[d0 - 1 - mid]) lo = mid + 1; else hi = mid;
  }
  int i = lo, j = d0 - lo;
  int end = d0 + cnt;
  if (end > nA + nB) end = nA + nB;
  if (end > outLimit) end = outLimit;
  for (int q = d0; q < end; ++q) {
    u64 v;
    if (i < nA && (j >= nB || A[i] <= B[j])) v = A[i++]; else v = B[j++];
    dst[q] = v;
  }
}

// ------- 4-way merge (2 levels in LDS), truncated to first 6016, 4 blocks ------
__global__ __launch_bounds__(256) void merge4_kernel(const u64* __restrict__ keys, u64* __restrict__ tmp) {
  __shared__ u64 M01[4096];
  __shared__ u64 M23[4096];
  const int tid = threadIdx.x;
  const u64* c = keys + (size_t)blockIdx.x * 8192;
  merge_path(c,        2048, c + 2048, 2048, M01, tid * 16, 16, 4096);
  merge_path(c + 4096, 2048, c + 6144, 2048, M23, tid * 16, 16, 4096);
  __syncthreads();
  merge_path(M01, 4096, M23, 4096, tmp + (size_t)blockIdx.x * TOPN, tid * 24, 24, TOPN);
}

// --- final: 4 lists of 6016 -> top-6016 (LDS) + fused gather (r6-verbatim) -----
__global__ __launch_bounds__(256) void mergefinal_gather_kernel(const u64* __restrict__ tmp,
                                                                const float* __restrict__ roi,
                                                                float* __restrict__ tb, float* __restrict__ areaArr,
                                                                u64* __restrict__ valw) {
  __shared__ u64 L0[TOPN];
  __shared__ u64 L1[TOPN];
  __shared__ u64 F[TOPN];
  const int tid = threadIdx.x;
  merge_path(tmp,            TOPN, tmp + TOPN,     TOPN, L0, tid * 24, 24, TOPN);
  merge_path(tmp + 2 * TOPN, TOPN, tmp + 3 * TOPN, TOPN, L1, tid * 24, 24, TOPN);
  __syncthreads();
  merge_path(L0, TOPN, L1, TOPN, F, tid * 24, 24, TOPN);
  __syncthreads();
  for (int j0 = 0; j0 < TOPN; j0 += 256) {
    int j = j0 + tid;
    u64 key = F[j];
    bool valid = (j < PRE) && ((unsigned)(key >> 32) < 0xFF800000u);   // score > -inf
    if (j < PRE) {
      unsigned idx = (unsigned)key;
      float4 bx = *(const float4*)&roi[(size_t)idx * 4];
      *(float4*)&tb[(size_t)j * 4] = bx;
      areaArr[j] = (bx.z - bx.x) * (bx.w - bx.y);
    }
    u64 mask = __ballot(valid);
    if ((tid & 63) == 0) {
      int wi = j >> 6;
      if (wi < NW) valw[wi] = mask;
    }
  }
}

// --------------- suppression bit-matrix MT[w][i]: bits j in word w -------------
__global__ __launch_bounds__(256) void mask_kernel(const float* __restrict__ tb, const float* __restrict__ areaArr,
                                                   u64* __restrict__ MT) {
  int linear = blockIdx.x * 256 + threadIdx.x;
  if (linear >= NW * PRE) return;
  int w = linear / PRE;
  int i = linear - w * PRE;
  u64 bits = 0;
  int jbase = w * 64;
  if (jbase + 63 > i) {
    float4 bi = *(const float4*)&tb[(size_t)i * 4];
    float ai = areaArr[i];
    int jend = jbase + 64; if (jend > PRE) jend = PRE;
    int jst = jbase > i + 1 ? jbase : i + 1;
    for (int j = jst; j < jend; ++j) {
      float4 bj = *(const float4*)&tb[(size_t)j * 4];
      float ty1 = fmaxf(bi.x, bj.x);
      float tx1 = fmaxf(bi.y, bj.y);
      float ty2 = fminf(bi.z, bj.z);
      float tx2 = fminf(bi.w, bj.w);
      float ih = ty2 - ty1; if (ih < 0.f) ih = 0.f;
      float iw = tx2 - tx1; if (iw < 0.f) iw = 0.f;
      float inter = ih * iw;
      float denom = ai + areaArr[j] - inter;
      if (denom < 1e-9f) denom = 1e-9f;
      if (inter / denom > 0.7f) bits |= (1ull << (j - jbase));
    }
  }
  MT[(size_t)w * MTS + i] = bits;
}

__device__ inline u64 shfl_u64(u64 v, int src) {
  int lo = __shfl((int)(unsigned)(v & 0xffffffffull), src, 64);
  int hi = __shfl((int)(unsigned)(v >> 32), src, 64);
  return ((u64)(unsigned)hi << 32) | (unsigned)lo;
}
__device__ inline u64 shfl_u64_xor(u64 v, int m) {
  int lo = __shfl_xor((int)(unsigned)(v & 0xffffffffull), m, 64);
  int hi = __shfl_xor((int)(unsigned)(v >> 32), m, 64);
  return ((u64)(unsigned)hi << 32) | (unsigned)lo;
}

// --------- single-wave greedy NMS, demand-pull rem (verbatim r6) ---------------
__global__ __launch_bounds__(64) void nms_scan_kernel(const u64* __restrict__ MT, const u64* __restrict__ valw,
                                                      const float* __restrict__ tb, float* __restrict__ out) {
  __shared__ int keepids[POST];
  const int lane = threadIdx.x;
  int kept = 0;
  bool done = false;
  for (int g = 0; g < NW && !done; ++g) {
    const u64* __restrict__ rowg = MT + (size_t)g * MTS;
    u64 rem = 0;
    for (int base = 0; base < kept; base += 64) {
      int kidx = base + lane;
      u64 v = (kidx < kept) ? rowg[keepids[kidx]] : 0ull;
      rem |= v;
    }
    #pragma unroll
    for (int s = 32; s > 0; s >>= 1) rem |= shfl_u64_xor(rem, s);
    int row = g * 64 + lane;
    u64 cur = (row < PRE) ? rowg[row] : 0ull;        // own-word suppression bits
    u64 remaining = valw[g] & ~rem;
    while (remaining) {                               // uniform across lanes
      int c = __builtin_ctzll(remaining);
      if (lane == 0) keepids[kept] = g * 64 + c;
      ++kept;
      if (kept >= POST) { done = true; break; }
      u64 cw = shfl_u64(cur, c);                      // broadcast lane c's word
      u64 above = (c == 63) ? 0ull : (~0ull << (c + 1));
      remaining = remaining & ~cw & above;
    }
  }
  __syncthreads();
  int kmax = kept < POST ? kept : POST;
  for (int rr = lane; rr < kmax; rr += 64) {
    float4 b = *(const float4*)&tb[(size_t)keepids[rr] * 4];
    *(float4*)&out[(size_t)rr * 4] = b;
  }
}

extern "C" void kernel_launch(void* const* d_in, const int* in_sizes, int n_in,
                              void* d_out, int out_size, void* d_ws, size_t ws_size,
                              hipStream_t stream) {
  (void)in_sizes; (void)n_in; (void)ws_size;
  const float* x  = (const float*)d_in[0];
  const float* w1 = (const float*)d_in[1];
  const float* b1 = (const float*)d_in[2];
  const float* lw = (const float*)d_in[3];
  const float* lb = (const float*)d_in[4];
  const float* sw = (const float*)d_in[5];
  const float* sb = (const float*)d_in[6];
  float* out = (float*)d_out;

  char* wp = (char*)d_ws;
  auto alloc = [&](size_t b) -> void* { void* p = wp; wp += (b + 255) & ~(size_t)255; return p; };
  float* xp      = (float*)alloc((size_t)CIN * PH * PW * 4);   // 4.26 MB
  float* wt      = (float*)alloc((size_t)4608 * CIN * 4);      // 9.44 MB
  float* part    = (float*)alloc((size_t)3 * CIN * HW * 4);    // 11.7 MB
  float* c2      = (float*)alloc((size_t)64 * HW * 4);
  float* roi     = (float*)alloc((size_t)NA * 4 * 4);
  u64*   keys    = (u64*)alloc((size_t)NSORT * 8);
  u64*   tmp     = (u64*)alloc((size_t)4 * TOPN * 8);
  float* tb      = (float*)alloc((size_t)PRE * 4 * 4);
  float* areaArr = (float*)alloc((size_t)PRE * 4);
  u64*   valw    = (u64*)alloc((size_t)NW * 8);
  u64*   MT      = (u64*)alloc((size_t)NW * MTS * 8);          // 4.52 MB

  hipMemsetAsync(d_out, 0, (size_t)out_size * 4, stream);

  prep_kernel<<<5184, 256, 0, stream>>>(x, xp, w1, wt);
  conv_gemm_kernel<<<dim3(8, 30, 3), 256, 0, stream>>>(wt, xp, part);
  relu_heads_kernel<<<(HW + PB - 1) / PB, 256, 0, stream>>>(part, b1, lw, sw, lb, sb, c2);
  decode_sort_kernel<<<16, 256, 0, stream>>>(c2, roi, keys);
  merge4_kernel<<<4, 256, 0, stream>>>(keys, tmp);
  mergefinal_gather_kernel<<<1, 256, 0, stream>>>(tmp, roi, tb, areaArr, valw);
  mask_kernel<<<(NW * PRE + 255) / 256, 256, 0, stream>>>(tb, areaArr, MT);
  nms_scan_kernel<<<1, 64, 0, stream>>>(MT, valw, tb, out);
}

// Round 13
// 464.466 us; speedup vs baseline: 1.1668x; 1.1668x over previous
//
#include <hip/hip_runtime.h>
#include <cstdint>
#include <cstddef>

typedef unsigned long long u64;

#define CIN   512
#define H     38
#define W     50
#define HW    1900
#define PH    40
#define PW    52
#define NA    17100
#define NSORT 32768
#define PRE   6000
#define POST  300
#define NW    94        // ceil(6000/64)
#define MTS   6016      // MT row stride (padded)
#define TOPN  6016      // padded top-k (>= PRE)
#define PB    8         // p-chunk for relu_heads (238 blocks ~ 1/CU)

// ANCHOR_BASE, fp32-exact decimal literals
__constant__ float c_AB[36] = {
  -37.254833f,  -82.50967f,   53.254833f,  98.50967f,
  -82.50967f,  -173.01933f,   98.50967f,  189.01933f,
 -173.01933f,  -354.03867f,  189.01933f,  370.03867f,
  -56.f, -56.f, 72.f, 72.f,
 -120.f,-120.f,136.f,136.f,
 -248.f,-248.f,264.f,264.f,
  -82.50967f,  -37.254833f,   98.50967f,  53.254833f,
 -173.01933f,  -82.50967f,   189.01933f,  98.50967f,
 -354.03867f, -173.01933f,   370.03867f, 189.01933f
};

// ----------------- fused prep: pad (4160 blks) + wtrans (1024 blks) ------------
__global__ __launch_bounds__(256) void prep_kernel(const float* __restrict__ x, float* __restrict__ xp,
                                                   const float* __restrict__ w1, float* __restrict__ wt) {
  __shared__ float tile[9][16][17];
  int b = blockIdx.x;
  if (b < 4160) {                                    // ---- pad ----
    int idx = b * 256 + threadIdx.x;                 // exactly 512*40*52
    int c   = idx / (PH * PW);
    int rem = idx - c * (PH * PW);
    int yy  = rem / PW;
    int xx  = rem - yy * PW;
    float v = 0.f;
    if (yy >= 1 && yy <= H && xx >= 1 && xx <= W)
      v = x[(size_t)c * HW + (yy - 1) * W + (xx - 1)];
    xp[idx] = v;
  } else {                                           // ---- wtrans ----
    int t2 = b - 4160;
    int o0 = (t2 & 31) * 16, i0 = (t2 >> 5) * 16;
    int tx = threadIdx.x & 15, ty = threadIdx.x >> 4;
    #pragma unroll
    for (int r = 0; r < 9; ++r)
      tile[r][tx][ty] = w1[((size_t)(o0 + ty) * CIN + (i0 + tx)) * 9 + r];
    __syncthreads();
    #pragma unroll
    for (int r = 0; r < 9; ++r)
      wt[((size_t)r * CIN + i0 + ty) * CIN + o0 + tx] = tile[r][ty][tx];
  }
}

// --------- conv1 as implicit GEMM, fp32, deterministic 3-way K-split ----------
// r0 configuration VERBATIM: 64x64 tile, 4x4 micro, 720 blocks (2.8 waves/SIMD).
// Counter-validated LDS-pipe wall: ds_read_b128 instrs x 12cyc / 256 CU = 171us
// == measured, VALUBusy ~61%. Five restructures (8x8/1-wave, no-LDS streaming,
// scalar-A, 128^2 tile, B-from-global) all lost to the LDS-pipe/occupancy/
// latency triangle -- the 16-kk staging granularity is what gives the compiler
// its prefetch window. Structural optimum for this fp32 shape. Bit-exact
// k-order (required: downstream sort+NMS are decision-discontinuous).
__global__ __launch_bounds__(256) void conv_gemm_kernel(const float* __restrict__ wt, const float* __restrict__ xp,
                                                        float* __restrict__ part) {
  __shared__ __align__(16) float As[16][64];
  __shared__ __align__(16) float Bs[16][64];
  const int tid   = threadIdx.x;
  const int obase = blockIdx.x * 64;
  const int pbase = blockIdx.y * 64;
  const int split = blockIdx.z;
  const int kbeg = split * 1536, kend = kbeg + 1536;
  const int krow = tid >> 4;          // staging row 0..15
  const int c4   = (tid & 15) * 4;    // staging col
  const int to   = (tid & 15) * 4;    // output o quad
  const int tp   = (tid >> 4) * 4;    // output p quad
  float acc[4][4] = {};
  float av[4], bv[4];

  auto loadAB = [&](int k0) {
    int k = k0 + krow;
    const float* ap = &wt[(size_t)k * CIN + obase + c4];
    av[0] = ap[0]; av[1] = ap[1]; av[2] = ap[2]; av[3] = ap[3];
    int r = k >> 9;            // k = r*512 + i
    int i = k & 511;
    int ky = r / 3, kx = r - ky * 3;
    const float* xpi = &xp[(size_t)i * (PH * PW)];
    #pragma unroll
    for (int j = 0; j < 4; ++j) {
      int p = pbase + c4 + j;
      float v = 0.f;
      if (p < HW) {
        int y = p / W, xx = p - y * W;
        v = xpi[(y + ky) * PW + xx + kx];
      }
      bv[j] = v;
    }
  };

  loadAB(kbeg);
  for (int k0 = kbeg; k0 < kend; k0 += 16) {
    __syncthreads();
    *(float4*)&As[krow][c4] = make_float4(av[0], av[1], av[2], av[3]);
    *(float4*)&Bs[krow][c4] = make_float4(bv[0], bv[1], bv[2], bv[3]);
    __syncthreads();
    if (k0 + 16 < kend) loadAB(k0 + 16);
    #pragma unroll
    for (int kk = 0; kk < 16; ++kk) {
      float4 a4 = *(const float4*)&As[kk][to];
      float4 b4 = *(const float4*)&Bs[kk][tp];
      float ar[4] = {a4.x, a4.y, a4.z, a4.w};
      float br[4] = {b4.x, b4.y, b4.z, b4.w};
      #pragma unroll
      for (int ii = 0; ii < 4; ++ii)
        #pragma unroll
        for (int jj = 0; jj < 4; ++jj)
          acc[ii][jj] += ar[ii] * br[jj];
    }
  }
  float* dst = part + (size_t)split * CIN * HW;
  #pragma unroll
  for (int ii = 0; ii < 4; ++ii) {
    int o = obase + to + ii;
    int p = pbase + tp;
    float* rowp = dst + (size_t)o * HW;
    if (p + 3 < HW) {
      *(float4*)&rowp[p] = make_float4(acc[ii][0], acc[ii][1], acc[ii][2], acc[ii][3]);
    } else {
      #pragma unroll
      for (int jj = 0; jj < 4; ++jj) if (p + jj < HW) rowp[p + jj] = acc[ii][jj];
    }
  }
}

// ---- fused relu+heads: h1 column slab in LDS, c2 out; h1 never materialized ---
__global__ __launch_bounds__(256) void relu_heads_kernel(const float* __restrict__ part, const float* __restrict__ b1,
                                                         const float* __restrict__ lw, const float* __restrict__ sw,
                                                         const float* __restrict__ lb, const float* __restrict__ sb,
                                                         float* __restrict__ c2) {
  __shared__ float h1c[CIN][PB];                     // 16KB
  const int tid = threadIdx.x;
  const int p0  = blockIdx.x * PB;
  // phase 1: relu slab
  for (int e = tid; e < CIN * PB; e += 256) {
    int o  = e >> 3;
    int pp = e & (PB - 1);
    int p  = p0 + pp;
    float v = 0.f;
    if (p < HW) {
      size_t idx = (size_t)o * HW + p;
      v = part[idx] + part[(size_t)CIN * HW + idx] + part[(size_t)2 * CIN * HW + idx] + b1[o];
      v = v > 0.f ? v : 0.f;
    }
    h1c[o][pp] = v;
  }
  __syncthreads();
  // phase 2: heads dots from LDS
  for (int u = tid; u < 54 * PB; u += 256) {
    int o  = u >> 3;
    int pp = u & (PB - 1);
    int p  = p0 + pp;
    const float* __restrict__ ap = (o < 36) ? (lw + (size_t)o * CIN) : (sw + (size_t)(o - 36) * CIN);
    float acc = 0.f;
    #pragma unroll 1
    for (int g = 0; g < CIN; g += 16) {
      float4 a0 = *(const float4*)(ap + g);
      float4 a1 = *(const float4*)(ap + g + 4);
      float4 a2 = *(const float4*)(ap + g + 8);
      float4 a3 = *(const float4*)(ap + g + 12);
      acc += a0.x * h1c[g +  0][pp];  acc += a0.y * h1c[g +  1][pp];
      acc += a0.z * h1c[g +  2][pp];  acc += a0.w * h1c[g +  3][pp];
      acc += a1.x * h1c[g +  4][pp];  acc += a1.y * h1c[g +  5][pp];
      acc += a1.z * h1c[g +  6][pp];  acc += a1.w * h1c[g +  7][pp];
      acc += a2.x * h1c[g +  8][pp];  acc += a2.y * h1c[g +  9][pp];
      acc += a2.z * h1c[g + 10][pp];  acc += a2.w * h1c[g + 11][pp];
      acc += a3.x * h1c[g + 12][pp];  acc += a3.y * h1c[g + 13][pp];
      acc += a3.z * h1c[g + 14][pp];  acc += a3.w * h1c[g + 15][pp];
    }
    if (p < HW) {
      float bias = (o < 36) ? lb[o] : sb[o - 36];
      c2[(size_t)o * HW + p] = acc + bias;
    }
  }
}

// ------- fused decode + LDS bitonic sort: 16 blocks, 2048 keys each ------------
__global__ __launch_bounds__(256) void decode_sort_kernel(const float* __restrict__ c2, float* __restrict__ roi,
                                                          u64* __restrict__ keys) {
  __shared__ u64 s[2048];
  const int tid = threadIdx.x;
  const int nbase = blockIdx.x * 2048;
  for (int i = tid; i < 2048; i += 256) {
    int n = nbase + i;
    u64 key;
    if (n >= NA) {
      key = ~0ull;
    } else {
      unsigned p = (unsigned)n / 9u;
      unsigned a = (unsigned)n - p * 9u;
      unsigned y = p / 50u;
      unsigned xu = p - y * 50u;
      float dy = c2[(a * 4 + 0) * HW + p];
      float dx = c2[(a * 4 + 1) * HW + p];
      float dh = c2[(a * 4 + 2) * HW + p];
      float dw = c2[(a * 4 + 3) * HW + p];
      float fg = c2[(37 + a * 2) * HW + p];         // score channel a*2+1, rows offset 36
      float sy = (float)(y * 16u), sx = (float)(xu * 16u);
      float ay1 = sy + c_AB[a * 4 + 0], ax1 = sx + c_AB[a * 4 + 1];
      float ay2 = sy + c_AB[a * 4 + 2], ax2 = sx + c_AB[a * 4 + 3];
      float ahh = ay2 - ay1, aww = ax2 - ax1;
      float acy = ay1 + 0.5f * ahh, acx = ax1 + 0.5f * aww;
      float cy = dy * ahh + acy, cx = dx * aww + acx;
      float hh = expf(dh) * ahh, ww = expf(dw) * aww;
      float y1 = cy - 0.5f * hh, x1 = cx - 0.5f * ww;
      float y2 = cy + 0.5f * hh, x2 = cx + 0.5f * ww;
      y1 = fminf(fmaxf(y1, 0.f), 608.f); x1 = fminf(fmaxf(x1, 0.f), 800.f);
      y2 = fminf(fmaxf(y2, 0.f), 608.f); x2 = fminf(fmaxf(x2, 0.f), 800.f);
      *(float4*)&roi[(size_t)n * 4] = make_float4(y1, x1, y2, x2);
      bool valid = ((y2 - y1) >= 16.f) && ((x2 - x1) >= 16.f);
      float sc = valid ? fg : -__builtin_huge_valf();
      unsigned m = __float_as_uint(sc);
      m = (m & 0x80000000u) ? ~m : (m | 0x80000000u);  // monotone map
      unsigned km = ~m;                                 // ascending = descending score
      key = ((u64)km << 32) | (unsigned)n;
    }
    s[i] = key;
  }
  __syncthreads();
  for (int k = 2; k <= 2048; k <<= 1) {
    for (int j = k >> 1; j > 0; j >>= 1) {
      for (int i = tid; i < 2048; i += 256) {
        int l = i ^ j;
        if (l > i) {
          u64 xa = s[i], xb = s[l];
          bool up = ((i & k) == 0);
          if ((xa > xb) == up) { s[i] = xb; s[l] = xa; }
        }
      }
      __syncthreads();
    }
  }
  for (int i = tid; i < 2048; i += 256) keys[nbase + i] = s[i];
}

// ------------------------------ merge-path helper ------------------------------
__device__ inline void merge_path(const u64* __restrict__ A, int nA, const u64* __restrict__ B, int nB,
                                  u64* __restrict__ dst, int d0, int cnt, int outLimit) {
  if (d0 >= outLimit || d0 >= nA + nB) return;
  int lo = d0 > nB ? d0 - nB : 0;
  int hi = d0 < nA ? d0 : nA;
  while (lo < hi) {
    int mid = (lo + hi) >> 1;
    if (A[mid] <= B[d0 - 1 - mid]) lo = mid + 1; else hi = mid;
  }
  int i = lo, j = d0 - lo;
  int end = d0 + cnt;
  if (end > nA + nB) end = nA + nB;
  if (end > outLimit) end = outLimit;
  for (int q = d0; q < end; ++q) {
    u64 v;
    if (i < nA && (j >= nB || A[i] <= B[j])) v = A[i++]; else v = B[j++];
    dst[q] = v;
  }
}

// ------- 4-way merge (2 levels in LDS), truncated to first 6016, 4 blocks ------
__global__ __launch_bounds__(256) void merge4_kernel(const u64* __restrict__ keys, u64* __restrict__ tmp) {
  __shared__ u64 M01[4096];
  __shared__ u64 M23[4096];
  const int tid = threadIdx.x;
  const u64* c = keys + (size_t)blockIdx.x * 8192;
  merge_path(c,        2048, c + 2048, 2048, M01, tid * 16, 16, 4096);
  merge_path(c + 4096, 2048, c + 6144, 2048, M23, tid * 16, 16, 4096);
  __syncthreads();
  merge_path(M01, 4096, M23, 4096, tmp + (size_t)blockIdx.x * TOPN, tid * 24, 24, TOPN);
}

// --- final: 4 lists of 6016 -> top-6016 (LDS) + fused gather (r6-verbatim) -----
__global__ __launch_bounds__(256) void mergefinal_gather_kernel(const u64* __restrict__ tmp,
                                                                const float* __restrict__ roi,
                                                                float* __restrict__ tb, float* __restrict__ areaArr,
                                                                u64* __restrict__ valw) {
  __shared__ u64 L0[TOPN];
  __shared__ u64 L1[TOPN];
  __shared__ u64 F[TOPN];
  const int tid = threadIdx.x;
  merge_path(tmp,            TOPN, tmp + TOPN,     TOPN, L0, tid * 24, 24, TOPN);
  merge_path(tmp + 2 * TOPN, TOPN, tmp + 3 * TOPN, TOPN, L1, tid * 24, 24, TOPN);
  __syncthreads();
  merge_path(L0, TOPN, L1, TOPN, F, tid * 24, 24, TOPN);
  __syncthreads();
  for (int j0 = 0; j0 < TOPN; j0 += 256) {
    int j = j0 + tid;
    u64 key = F[j];
    bool valid = (j < PRE) && ((unsigned)(key >> 32) < 0xFF800000u);   // score > -inf
    if (j < PRE) {
      unsigned idx = (unsigned)key;
      float4 bx = *(const float4*)&roi[(size_t)idx * 4];
      *(float4*)&tb[(size_t)j * 4] = bx;
      areaArr[j] = (bx.z - bx.x) * (bx.w - bx.y);
    }
    u64 mask = __ballot(valid);
    if ((tid & 63) == 0) {
      int wi = j >> 6;
      if (wi < NW) valw[wi] = mask;
    }
  }
}

// --------------- suppression bit-matrix MT[w][i]: bits j in word w -------------
__global__ __launch_bounds__(256) void mask_kernel(const float* __restrict__ tb, const float* __restrict__ areaArr,
                                                   u64* __restrict__ MT) {
  int linear = blockIdx.x * 256 + threadIdx.x;
  if (linear >= NW * PRE) return;
  int w = linear / PRE;
  int i = linear - w * PRE;
  u64 bits = 0;
  int jbase = w * 64;
  if (jbase + 63 > i) {
    float4 bi = *(const float4*)&tb[(size_t)i * 4];
    float ai = areaArr[i];
    int jend = jbase + 64; if (jend > PRE) jend = PRE;
    int jst = jbase > i + 1 ? jbase : i + 1;
    for (int j = jst; j < jend; ++j) {
      float4 bj = *(const float4*)&tb[(size_t)j * 4];
      float ty1 = fmaxf(bi.x, bj.x);
      float tx1 = fmaxf(bi.y, bj.y);
      float ty2 = fminf(bi.z, bj.z);
      float tx2 = fminf(bi.w, bj.w);
      float ih = ty2 - ty1; if (ih < 0.f) ih = 0.f;
      float iw = tx2 - tx1; if (iw < 0.f) iw = 0.f;
      float inter = ih * iw;
      float denom = ai + areaArr[j] - inter;
      if (denom < 1e-9f) denom = 1e-9f;
      if (inter / denom > 0.7f) bits |= (1ull << (j - jbase));
    }
  }
  MT[(size_t)w * MTS + i] = bits;
}

__device__ inline u64 shfl_u64(u64 v, int src) {
  int lo = __shfl((int)(unsigned)(v & 0xffffffffull), src, 64);
  int hi = __shfl((int)(unsigned)(v >> 32), src, 64);
  return ((u64)(unsigned)hi << 32) | (unsigned)lo;
}
__device__ inline u64 shfl_u64_xor(u64 v, int m) {
  int lo = __shfl_xor((int)(unsigned)(v & 0xffffffffull), m, 64);
  int hi = __shfl_xor((int)(unsigned)(v >> 32), m, 64);
  return ((u64)(unsigned)hi << 32) | (unsigned)lo;
}

// --------- single-wave greedy NMS, demand-pull rem (verbatim r6) ---------------
__global__ __launch_bounds__(64) void nms_scan_kernel(const u64* __restrict__ MT, const u64* __restrict__ valw,
                                                      const float* __restrict__ tb, float* __restrict__ out) {
  __shared__ int keepids[POST];
  const int lane = threadIdx.x;
  int kept = 0;
  bool done = false;
  for (int g = 0; g < NW && !done; ++g) {
    const u64* __restrict__ rowg = MT + (size_t)g * MTS;
    u64 rem = 0;
    for (int base = 0; base < kept; base += 64) {
      int kidx = base + lane;
      u64 v = (kidx < kept) ? rowg[keepids[kidx]] : 0ull;
      rem |= v;
    }
    #pragma unroll
    for (int s = 32; s > 0; s >>= 1) rem |= shfl_u64_xor(rem, s);
    int row = g * 64 + lane;
    u64 cur = (row < PRE) ? rowg[row] : 0ull;        // own-word suppression bits
    u64 remaining = valw[g] & ~rem;
    while (remaining) {                               // uniform across lanes
      int c = __builtin_ctzll(remaining);
      if (lane == 0) keepids[kept] = g * 64 + c;
      ++kept;
      if (kept >= POST) { done = true; break; }
      u64 cw = shfl_u64(cur, c);                      // broadcast lane c's word
      u64 above = (c == 63) ? 0ull : (~0ull << (c + 1));
      remaining = remaining & ~cw & above;
    }
  }
  __syncthreads();
  int kmax = kept < POST ? kept : POST;
  for (int rr = lane; rr < kmax; rr += 64) {
    float4 b = *(const float4*)&tb[(size_t)keepids[rr] * 4];
    *(float4*)&out[(size_t)rr * 4] = b;
  }
}

extern "C" void kernel_launch(void* const* d_in, const int* in_sizes, int n_in,
                              void* d_out, int out_size, void* d_ws, size_t ws_size,
                              hipStream_t stream) {
  (void)in_sizes; (void)n_in; (void)ws_size;
  const float* x  = (const float*)d_in[0];
  const float* w1 = (const float*)d_in[1];
  const float* b1 = (const float*)d_in[2];
  const float* lw = (const float*)d_in[3];
  const float* lb = (const float*)d_in[4];
  const float* sw = (const float*)d_in[5];
  const float* sb = (const float*)d_in[6];
  float* out = (float*)d_out;

  char* wp = (char*)d_ws;
  auto alloc = [&](size_t b) -> void* { void* p = wp; wp += (b + 255) & ~(size_t)255; return p; };
  float* xp      = (float*)alloc((size_t)CIN * PH * PW * 4);   // 4.26 MB
  float* wt      = (float*)alloc((size_t)4608 * CIN * 4);      // 9.44 MB
  float* part    = (float*)alloc((size_t)3 * CIN * HW * 4);    // 11.7 MB
  float* c2      = (float*)alloc((size_t)64 * HW * 4);
  float* roi     = (float*)alloc((size_t)NA * 4 * 4);
  u64*   keys    = (u64*)alloc((size_t)NSORT * 8);
  u64*   tmp     = (u64*)alloc((size_t)4 * TOPN * 8);
  float* tb      = (float*)alloc((size_t)PRE * 4 * 4);
  float* areaArr = (float*)alloc((size_t)PRE * 4);
  u64*   valw    = (u64*)alloc((size_t)NW * 8);
  u64*   MT      = (u64*)alloc((size_t)NW * MTS * 8);          // 4.52 MB

  hipMemsetAsync(d_out, 0, (size_t)out_size * 4, stream);

  prep_kernel<<<5184, 256, 0, stream>>>(x, xp, w1, wt);
  conv_gemm_kernel<<<dim3(8, 30, 3), 256, 0, stream>>>(wt, xp, part);
  relu_heads_kernel<<<(HW + PB - 1) / PB, 256, 0, stream>>>(part, b1, lw, sw, lb, sb, c2);
  decode_sort_kernel<<<16, 256, 0, stream>>>(c2, roi, keys);
  merge4_kernel<<<4, 256, 0, stream>>>(keys, tmp);
  mergefinal_gather_kernel<<<1, 256, 0, stream>>>(tmp, roi, tb, areaArr, valw);
  mask_kernel<<<(NW * PRE + 255) / 256, 256, 0, stream>>>(tb, areaArr, MT);
  nms_scan_kernel<<<1, 64, 0, stream>>>(MT, valw, tb, out);
}